// Round 13
// baseline (349.857 us; speedup 1.0000x reference)
//
#include <hip/hip_runtime.h>

typedef float f32x4 __attribute__((ext_vector_type(4)));
typedef float f32x2 __attribute__((ext_vector_type(2)));
typedef _Float16 f16x8 __attribute__((ext_vector_type(8)));
typedef _Float16 f16x4 __attribute__((ext_vector_type(4)));
typedef _Float16 f16x2 __attribute__((ext_vector_type(2)));

__device__ __forceinline__ float tanh_fast(float x) {
  float e = __builtin_amdgcn_exp2f(x * 2.885390081777927f);
  return 1.0f - 2.0f * __builtin_amdgcn_rcpf(e + 1.0f);
}

// Device-scope dataflow sync (XCD-safe: agent-scope release/acquire).
__device__ __forceinline__ void wait_cnt(int* p, int target) {
  if (threadIdx.x == 0) {
    while (__hip_atomic_load(p, __ATOMIC_RELAXED, __HIP_MEMORY_SCOPE_AGENT) < target)
      __builtin_amdgcn_s_sleep(2);
    (void)__hip_atomic_load(p, __ATOMIC_ACQUIRE, __HIP_MEMORY_SCOPE_AGENT);
  }
  __syncthreads();
}
__device__ __forceinline__ void publish_cnt(int* p) {
  __syncthreads();   // full vmcnt/lgkm drain: all threads' stores complete
  if (threadIdx.x == 0)
    (void)__hip_atomic_fetch_add(p, 1, __ATOMIC_RELEASE, __HIP_MEMORY_SCOPE_AGENT);
}

// ---------------------------------------------------------------------------
// Plain transpose + cast fp32 -> f16:  out[C][R] = (f16) in[R][C]
// ---------------------------------------------------------------------------
__global__ __launch_bounds__(256) void k_transpose_cast(
    const float* __restrict__ in, _Float16* __restrict__ outp, int R, int C)
{
  __shared__ float tile[32][33];
  const int tx = threadIdx.x & 31, ty = threadIdx.x >> 5;
  const int tc = blockIdx.x * 32, tr = blockIdx.y * 32;
#pragma unroll
  for (int i = 0; i < 32; i += 8)
    tile[ty + i][tx] = in[(size_t)(tr + ty + i) * C + tc + tx];
  __syncthreads();
#pragma unroll
  for (int i = 0; i < 32; i += 8)
    outp[(size_t)(tc + ty + i) * R + tr + tx] = (_Float16)tile[tx][ty + i];
}

// ---------------------------------------------------------------------------
// Permuted transpose + cast: out[c][pinv(r)] = (f16) in[r][c]
// pinv(r) = (r&~31) | ((r&15)<<1) | ((r>>4)&1)    (32-block k-permutation)
// ---------------------------------------------------------------------------
__global__ __launch_bounds__(256) void k_transpose_cast_perm(
    const float* __restrict__ in, _Float16* __restrict__ outp, int R, int C)
{
  __shared__ float tile[32][33];
  const int tx = threadIdx.x & 31, ty = threadIdx.x >> 5;
  const int tc = blockIdx.x * 32, tr = blockIdx.y * 32;
#pragma unroll
  for (int i = 0; i < 32; i += 8)
    tile[ty + i][tx] = in[(size_t)(tr + ty + i) * C + tc + tx];
  __syncthreads();
  const int r = tr + tx;
  const int p = (r & ~31) | ((r & 15) << 1) | ((r >> 4) & 1);
#pragma unroll
  for (int i = 0; i < 32; i += 8)
    outp[(size_t)(tc + ty + i) * R + p] = (_Float16)tile[tx][ty + i];
}

// ===========================================================================
// FUSED persistent kernel: 256 blocks x 512 threads, 84KB dyn LDS -> 1/CU.
//   0..7     scan (chunked 16 x 32 steps; depth-8 double-banked xp prefetch)
//   8..191   persistent GEMM1 (512 tiles; publishes cnt1[tc] per tile)
//   192..255 persistent GEMM3+softmax (1024 tiles; waits sc[chunk])
// ===========================================================================
__global__ __launch_bounds__(512, 1) void k_fused(
    const float* __restrict__ X, const _Float16* __restrict__ WxT,
    const float* __restrict__ bias, float* __restrict__ xp_packed,
    const _Float16* __restrict__ WhTp, _Float16* __restrict__ Yt,
    float* __restrict__ hT,
    const _Float16* __restrict__ WdTp, const float* __restrict__ bd,
    float* __restrict__ out, int* cnt1, int* sc)
{
  extern __shared__ char smem[];
  const int bid = blockIdx.x;
  const int tid = threadIdx.x;
  const int lane = tid & 63, w = tid >> 6;
  const int l15 = lane & 15, lq = lane >> 4;

  if (bid < 8) {
    // ----------------------------- SCAN ---------------------------------
    const int g = bid;
    char* hz = smem;                       // 2 x 4224 B h ping-pong
    for (int i = tid; i < 2112; i += 512) ((float*)hz)[i] = 0.f;

    f16x8 bf[2][8];
#pragma unroll
    for (int j = 0; j < 2; ++j)
#pragma unroll
      for (int i = 0; i < 8; ++i) {
        int ks = (w + i) & 7;
        bf[j][i] = *(const f16x8*)(WhTp + (w * 32 + j * 16 + l15) * 256 + ks * 32 + lq * 8);
      }

    const int rd_base = (l15 & 3) * 1056 + w * 64 + lq * 16;
    const int wr_base = lq * 1056 + w * 64 + l15 * 4;
    const bool m1 = (lq & 1) != 0, m2 = (lq & 2) != 0;

    const float* xpb = xp_packed + ((size_t)g * 8 + w) * 128 + lane * 2;
    _Float16* yb = Yt + ((size_t)(g * 4 + lq)) * 256 + w * 32 + l15 * 2;
    float* hTb = hT + (g * 4 + lq) * 256 + w * 32 + l15;

    wait_cnt(cnt1 + 0, 32);                // xp chunk 0 ready (also syncs init)

    // depth-8 double-banked xp pipeline
    f32x2 xa0, xa1, xa2, xa3, xa4, xa5, xa6, xa7;
    f32x2 xb0, xb1, xb2, xb3, xb4, xb5, xb6, xb7;
#define LOADX(XR, TN)                                                          \
    { int tn_ = (TN); if (tn_ > 511) tn_ = 511;                                \
      XR = *(const f32x2*)(xpb + (size_t)tn_ * 8192); }
    LOADX(xa0, 0) LOADX(xa1, 1) LOADX(xa2, 2) LOADX(xa3, 3)
    LOADX(xa4, 4) LOADX(xa5, 5) LOADX(xa6, 6) LOADX(xa7, 7)

#define SCAN_STEP(T, CUR, XR)                                                  \
  {                                                                            \
    const int t = (T);                                                         \
    f16x8 af[8];                                                               \
    af[0] = *(const f16x8*)(hz + rd_base + (CUR) * 4224 + 0 * 64);             \
    asm volatile("" ::: "memory");                                             \
    __builtin_amdgcn_s_barrier();                                              \
    asm volatile("" ::: "memory");                                             \
    _Pragma("unroll")                                                          \
    for (int i = 1; i < 8; ++i)                                                \
      af[i] = *(const f16x8*)(hz + rd_base + (CUR) * 4224 + i * 64);           \
    f32x2 xcur = XR;                                                           \
    f32x4 acc[2][4];                                                           \
    _Pragma("unroll")                                                          \
    for (int j = 0; j < 2; ++j) {                                              \
      _Pragma("unroll")                                                        \
      for (int c2 = 0; c2 < 4; ++c2) {                                         \
        f32x4 zz = {0.f, 0.f, 0.f, 0.f};                                       \
        acc[j][c2] = __builtin_amdgcn_mfma_f32_16x16x32_f16(af[2 * c2], bf[j][2 * c2], zz, 0, 0, 0); \
      }                                                                        \
    }                                                                          \
    _Pragma("unroll")                                                          \
    for (int j = 0; j < 2; ++j) {                                              \
      _Pragma("unroll")                                                        \
      for (int c2 = 0; c2 < 4; ++c2)                                           \
        acc[j][c2] = __builtin_amdgcn_mfma_f32_16x16x32_f16(af[2 * c2 + 1], bf[j][2 * c2 + 1], acc[j][c2], 0, 0, 0); \
    }                                                                          \
    f16x2 h2;                                                                  \
    float vv[2];                                                               \
    _Pragma("unroll")                                                          \
    for (int j = 0; j < 2; ++j) {                                              \
      f32x4 s01 = acc[j][0] + acc[j][1];                                       \
      f32x4 s23 = acc[j][2] + acc[j][3];                                       \
      f32x4 s = s01 + s23;                                                     \
      float t0 = m1 ? s[1] : s[0];                                             \
      float t1 = m1 ? s[3] : s[2];                                             \
      float v = tanh_fast((m2 ? t1 : t0) + xcur[j]);                           \
      vv[j] = v;                                                               \
      h2[j] = (_Float16)v;                                                     \
    }                                                                          \
    *(f16x2*)(hz + wr_base + ((CUR) ^ 1) * 4224) = h2;                         \
    *(f16x2*)(hz + wr_base + ((CUR) ^ 1) * 4224 + 512) = h2;                   \
    *(f16x2*)(yb + (size_t)t * 8192) = h2;                                     \
    if (t == 511) { hTb[0] = vv[0]; hTb[16] = vv[1]; }                         \
    asm volatile("s_waitcnt lgkmcnt(0)" ::: "memory");                         \
  }

    // group of 8 steps: issue next group's loads into L*, consume C*
#define G8(B, C0, C1, C2, C3, C4, C5, C6, C7, L0, L1, L2, L3, L4, L5, L6, L7)  \
    LOADX(L0, (B) + 8)  LOADX(L1, (B) + 9)  LOADX(L2, (B) + 10)                \
    LOADX(L3, (B) + 11) LOADX(L4, (B) + 12) LOADX(L5, (B) + 13)                \
    LOADX(L6, (B) + 14) LOADX(L7, (B) + 15)                                    \
    SCAN_STEP((B) + 0, 0, C0) SCAN_STEP((B) + 1, 1, C1)                        \
    SCAN_STEP((B) + 2, 0, C2) SCAN_STEP((B) + 3, 1, C3)                        \
    SCAN_STEP((B) + 4, 0, C4) SCAN_STEP((B) + 5, 1, C5)                        \
    SCAN_STEP((B) + 6, 0, C6) SCAN_STEP((B) + 7, 1, C7)

    for (int c = 0; c < 16; ++c) {
      wait_cnt(cnt1 + (c < 15 ? c + 1 : 15), 32);   // xp for chunk c+1 ready
      const int tb = c * 32;
      G8(tb,      xa0, xa1, xa2, xa3, xa4, xa5, xa6, xa7,
                  xb0, xb1, xb2, xb3, xb4, xb5, xb6, xb7)
      G8(tb + 8,  xb0, xb1, xb2, xb3, xb4, xb5, xb6, xb7,
                  xa0, xa1, xa2, xa3, xa4, xa5, xa6, xa7)
      G8(tb + 16, xa0, xa1, xa2, xa3, xa4, xa5, xa6, xa7,
                  xb0, xb1, xb2, xb3, xb4, xb5, xb6, xb7)
      G8(tb + 24, xb0, xb1, xb2, xb3, xb4, xb5, xb6, xb7,
                  xa0, xa1, xa2, xa3, xa4, xa5, xa6, xa7)
      publish_cnt(sc + c);                           // Yt chunk c visible
    }
#undef G8
#undef SCAN_STEP
#undef LOADX

  } else if (bid < 192) {
    // --------------------- GEMM1 (512-thread version) -------------------
    // BM=32, BN=256, BK=64. Waves: wm=w&1 (m-tile), wn=w>>1 (64-col group).
    const int p = bid - 8;                 // 0..183
    _Float16 (*As)[72] = (_Float16(*)[72])smem;                 // 32 x 72
    _Float16 (*Bs)[72] = (_Float16(*)[72])(smem + 4608);        // 256 x 72
    const int wm = w & 1, wn = w >> 1;     // wm 0..1, wn 0..3

    for (int v = p; v < 512; v += 184) {
      const int tc = v >> 5, b = v & 31;
      const int m0 = b * 512 + tc * 32;

      f32x4 acc[4];
#pragma unroll
      for (int i = 0; i < 4; ++i) acc[i] = (f32x4){0.f, 0.f, 0.f, 0.f};

      for (int kc = 0; kc < 16; ++kc) {
        const int k0 = kc * 64;
        __syncthreads();                   // protect As/Bs from prior readers
        {                                  // stage A: 32 x 64, 1 f32x4/thread
          int r = tid >> 4, k4 = (tid & 15) * 4;
          f32x4 vv = *(const f32x4*)(X + (size_t)(m0 + r) * 1024 + k0 + k4);
          f16x4 hv;
          hv[0] = (_Float16)vv[0]; hv[1] = (_Float16)vv[1];
          hv[2] = (_Float16)vv[2]; hv[3] = (_Float16)vv[3];
          *(f16x4*)(&As[r][k4]) = hv;
        }
#pragma unroll
        for (int it = 0; it < 4; ++it) {   // stage B: 256 x 64 f16
          int q = tid + it * 512;          // 0..2047
          int n = q >> 3, k8 = (q & 7) * 8;
          *(f16x8*)(&Bs[n][k8]) = *(const f16x8*)(WxT + (size_t)n * 1024 + k0 + k8);
        }
        __syncthreads();
        f16x8 a[2];
#pragma unroll
        for (int ks = 0; ks < 2; ++ks)
          a[ks] = *(const f16x8*)(&As[wm * 16 + l15][ks * 32 + lq * 8]);
#pragma unroll
        for (int ct = 0; ct < 4; ++ct) {
#pragma unroll
          for (int ks = 0; ks < 2; ++ks) {
            f16x8 bfr = *(const f16x8*)(&Bs[wn * 64 + ct * 16 + l15][ks * 32 + lq * 8]);
            acc[ct] = __builtin_amdgcn_mfma_f32_16x16x32_f16(a[ks], bfr, acc[ct], 0, 0, 0);
          }
        }
      }
#pragma unroll
      for (int ct = 0; ct < 4; ++ct) {
        int ncol = wn * 64 + ct * 16 + l15;          // < 256
        float bvv = bias[ncol];
        int w_s = ncol >> 5, j_s = (ncol >> 4) & 1, i_s = ncol & 15;
#pragma unroll
        for (int r = 0; r < 4; ++r) {
          int m = m0 + wm * 16 + lq * 4 + r;         // m = b*512 + t
          int tt = m & 511, bb = m >> 9;
          int g_s = bb >> 2, lq_s = bb & 3;
          size_t idx = (((size_t)tt * 8 + g_s) * 8 + w_s) * 128 + (lq_s * 16 + i_s) * 2 + j_s;
          xp_packed[idx] = acc[ct][r] + bvv;
        }
      }
      publish_cnt(cnt1 + tc);
    }

  } else {
    // ------------------------- GEMM3 + softmax --------------------------
    const int q = bid - 192;               // 0..63
    _Float16 (*As)[264]  = (_Float16(*)[264])smem;               // 16 x 264
    _Float16 (*Bs)[136]  = (_Float16(*)[136])(smem + 8448);      // 128 x 136
    _Float16 (*lg)[1040] = (_Float16(*)[1040])(smem + 43264);    // 16 x 1040

    for (int v = q; v < 1024; v += 64) {
      const int b = v & 31, t0 = (v >> 5) * 16;
      const int m0 = b * 512 + t0;
      wait_cnt(sc + (t0 >> 5), 8);         // Yt chunk ready (also LDS-reuse sync)

      {
        int r = tid >> 5, k8 = (tid & 31) * 8;
        *(f16x8*)(&As[r][k8]) = *(const f16x8*)(Yt + ((size_t)(t0 + r) * 32 + b) * 256 + k8);
      }
      __syncthreads();
      f16x8 a[8];
#pragma unroll
      for (int ks = 0; ks < 8; ++ks)
        a[ks] = *(const f16x8*)(&As[l15][ks * 32 + lq * 8]);

      for (int cc = 0; cc < 8; ++cc) {
        const int c0 = cc * 128;
        const int ncol = c0 + w * 16 + l15;
        f32x4 acc = {0.f, 0.f, 0.f, 0.f};
        __syncthreads();
#pragma unroll
        for (int i = 0; i < 4; ++i) {
          int q2 = i * 512 + tid;
          int n = q2 >> 4, k8 = (q2 & 15) * 8;
          *(f16x8*)(&Bs[n][k8]) = *(const f16x8*)(WdTp + (size_t)(c0 + n) * 256 + k8);
        }
        __syncthreads();
#pragma unroll
        for (int ks = 0; ks < 4; ++ks) {
          f16x8 bfr = *(const f16x8*)(&Bs[w * 16 + l15][ks * 32 + lq * 8]);
          acc = __builtin_amdgcn_mfma_f32_16x16x32_f16(a[ks], bfr, acc, 0, 0, 0);
        }
        __syncthreads();
#pragma unroll
        for (int i = 0; i < 4; ++i) {
          int q2 = i * 512 + tid;
          int n = q2 >> 4, k8 = (q2 & 15) * 8;
          *(f16x8*)(&Bs[n][k8]) = *(const f16x8*)(WdTp + (size_t)(c0 + n) * 256 + 128 + k8);
        }
        __syncthreads();
#pragma unroll
        for (int ks = 4; ks < 8; ++ks) {
          f16x8 bfr = *(const f16x8*)(&Bs[w * 16 + l15][(ks - 4) * 32 + lq * 8]);
          acc = __builtin_amdgcn_mfma_f32_16x16x32_f16(a[ks], bfr, acc, 0, 0, 0);
        }
        float bvv = bd[ncol];
#pragma unroll
        for (int r = 0; r < 4; ++r)
          lg[lq * 4 + r][ncol] = (_Float16)(acc[r] + bvv);
      }
      __syncthreads();

      const int row = tid >> 5, j = tid & 31;
      float mx = -1e30f;
#pragma unroll
      for (int k = 0; k < 32; ++k)
        mx = fmaxf(mx, (float)lg[row][j + k * 32]);
#pragma unroll
      for (int m = 1; m < 32; m <<= 1)
        mx = fmaxf(mx, __shfl_xor(mx, m, 64));
      float s = 0.f;
#pragma unroll
      for (int k = 0; k < 32; ++k)
        s += __builtin_amdgcn_exp2f(((float)lg[row][j + k * 32] - mx) * 1.44269504088896f);
#pragma unroll
      for (int m = 1; m < 32; m <<= 1)
        s += __shfl_xor(s, m, 64);
      const float rinv = __builtin_amdgcn_rcpf(s);
      float* orow = out + (size_t)(m0 + row) * 1024;
#pragma unroll
      for (int k = 0; k < 8; ++k) {
        int c = k * 128 + j * 4;
        f32x4 vv;
#pragma unroll
        for (int u = 0; u < 4; ++u)
          vv[u] = __builtin_amdgcn_exp2f(((float)lg[row][c + u] - mx) * 1.44269504088896f) * rinv;
        *(f32x4*)(orow + c) = vv;
      }
      __syncthreads();                     // lg readers done before next tile
    }
  }
}

// ---------------------------------------------------------------------------
extern "C" void kernel_launch(void* const* d_in, const int* in_sizes, int n_in,
                              void* d_out, int out_size, void* d_ws, size_t ws_size,
                              hipStream_t stream) {
  const float* X  = (const float*)d_in[0];
  const float* Wx = (const float*)d_in[1];
  const float* Wh = (const float*)d_in[2];
  const float* bv = (const float*)d_in[3];
  const float* Wd = (const float*)d_in[4];
  const float* bd = (const float*)d_in[5];
  float* out = (float*)d_out;

  char* ws = (char*)d_ws;
  float*    xp_packed = (float*)(ws);                              // 16 MB
  _Float16* Yt    = (_Float16*)(ws + (16u << 20));                 // 8 MB
  _Float16* WxT   = (_Float16*)(ws + (24u << 20));                 // 512 KB
  _Float16* WhTp  = (_Float16*)(ws + (24u << 20) + (512u << 10));  // 128 KB
  _Float16* WdTp  = (_Float16*)(ws + (24u << 20) + (640u << 10));  // 512 KB
  int*      cnt1  = (int*)(ws + (26u << 20));                      // 16 ints
  int*      sc    = cnt1 + 16;                                     // 16 ints

  (void)hipFuncSetAttribute((const void*)k_fused,
                            hipFuncAttributeMaxDynamicSharedMemorySize, 86016);

  (void)hipMemsetAsync(cnt1, 0, 128, stream);
  k_transpose_cast<<<dim3(8, 32), 256, 0, stream>>>(Wx, WxT, 1024, 256);
  k_transpose_cast_perm<<<dim3(8, 8),  256, 0, stream>>>(Wh, WhTp, 256, 256);
  k_transpose_cast_perm<<<dim3(32, 8), 256, 0, stream>>>(Wd, WdTp, 256, 1024);
  k_fused<<<dim3(256), dim3(512), 86016, stream>>>(
      X, WxT, bv, xp_packed, WhTp, Yt, out + 16384 * 1024, WdTp, bd, out,
      cnt1, sc);
}

// Round 14
// 309.815 us; speedup vs baseline: 1.1292x; 1.1292x over previous
//
#include <hip/hip_runtime.h>

typedef float f32x4 __attribute__((ext_vector_type(4)));
typedef float f32x2 __attribute__((ext_vector_type(2)));
typedef _Float16 f16x8 __attribute__((ext_vector_type(8)));
typedef _Float16 f16x4 __attribute__((ext_vector_type(4)));
typedef _Float16 f16x2 __attribute__((ext_vector_type(2)));

__device__ __forceinline__ float tanh_fast(float x) {
  float e = __builtin_amdgcn_exp2f(x * 2.885390081777927f);
  return 1.0f - 2.0f * __builtin_amdgcn_rcpf(e + 1.0f);
}

// ---------------------------------------------------------------------------
// Merged transpose+cast kernel (one launch, 3 jobs by block range):
//   0..255   Wx  plain  (1024x256 -> WxT)
//   256..319 Wh  perm   (256x256  -> WhTp)
//   320..575 Wd  perm   (256x1024 -> WdTp)
// perm: out[c][pinv(r)], pinv(r) = (r&~31) | ((r&15)<<1) | ((r>>4)&1)
// ---------------------------------------------------------------------------
__global__ __launch_bounds__(256) void k_transpose_all(
    const float* __restrict__ Wx, _Float16* __restrict__ WxT,
    const float* __restrict__ Wh, _Float16* __restrict__ WhTp,
    const float* __restrict__ Wd, _Float16* __restrict__ WdTp)
{
  __shared__ float tile[32][33];
  const int b = blockIdx.x;
  const float* in; _Float16* outp; int R, C, bx, by, perm;
  if (b < 256)      { in = Wx; outp = WxT;  R = 1024; C = 256;  bx = b & 7;          by = b >> 3;          perm = 0; }
  else if (b < 320) { in = Wh; outp = WhTp; R = 256;  C = 256;  bx = (b - 256) & 7;  by = (b - 256) >> 3;  perm = 1; }
  else              { in = Wd; outp = WdTp; R = 256;  C = 1024; bx = (b - 320) & 31; by = (b - 320) >> 5;  perm = 1; }

  const int tx = threadIdx.x & 31, ty = threadIdx.x >> 5;
  const int tc = bx * 32, tr = by * 32;
#pragma unroll
  for (int i = 0; i < 32; i += 8)
    tile[ty + i][tx] = in[(size_t)(tr + ty + i) * C + tc + tx];
  __syncthreads();
  const int r = tr + tx;
  const int p = perm ? ((r & ~31) | ((r & 15) << 1) | ((r >> 4) & 1)) : r;
#pragma unroll
  for (int i = 0; i < 32; i += 8)
    outp[(size_t)(tc + ty + i) * R + p] = (_Float16)tile[tx][ty + i];
}

// ---------------------------------------------------------------------------
// GEMM1: xproj = X @ Wx + b, scattered into the scan's packed layout.
// BM=32 -> 512 blocks (2/CU, 42KB LDS) for cross-block latency hiding.
//   idx = ((t*8 + g)*8 + w)*128 + (lq*16 + i)*2 + j
//   where batch = g*4 + lq, col = w*32 + j*16 + i
// ---------------------------------------------------------------------------
__global__ __launch_bounds__(256) void k_gemm1(
    const float* __restrict__ X, const _Float16* __restrict__ WxT,
    const float* __restrict__ bias, float* __restrict__ xp_packed)
{
  __shared__ _Float16 As[32][72];
  __shared__ _Float16 Bs[256][72];
  const int tid = threadIdx.x;
  const int lane = tid & 63, w = tid >> 6;
  const int l15 = lane & 15, lq = lane >> 4;
  const int m0 = blockIdx.x * 32;
  const int wm = w & 1, wn = w >> 1;     // m-tile, n-group (128 cols)

  f32x4 acc[8];
#pragma unroll
  for (int i = 0; i < 8; ++i) acc[i] = (f32x4){0.f, 0.f, 0.f, 0.f};

  for (int kc = 0; kc < 16; ++kc) {
    const int k0 = kc * 64;
#pragma unroll
    for (int it = 0; it < 2; ++it) {
      int q = tid + it * 256;            // 0..511
      int r = q >> 4, k4 = (q & 15) * 4;
      f32x4 v = *(const f32x4*)(X + (size_t)(m0 + r) * 1024 + k0 + k4);
      f16x4 hv;
      hv[0] = (_Float16)v[0]; hv[1] = (_Float16)v[1];
      hv[2] = (_Float16)v[2]; hv[3] = (_Float16)v[3];
      *(f16x4*)(&As[r][k4]) = hv;
    }
#pragma unroll
    for (int it = 0; it < 8; ++it) {
      int q = tid + it * 256;
      int n = q >> 3, k8 = (q & 7) * 8;
      *(f16x8*)(&Bs[n][k8]) = *(const f16x8*)(WxT + (size_t)n * 1024 + k0 + k8);
    }
    __syncthreads();
    f16x8 a[2];
#pragma unroll
    for (int ks = 0; ks < 2; ++ks)
      a[ks] = *(const f16x8*)(&As[wm * 16 + l15][ks * 32 + lq * 8]);
#pragma unroll
    for (int ct = 0; ct < 8; ++ct) {
#pragma unroll
      for (int ks = 0; ks < 2; ++ks) {
        f16x8 bfr = *(const f16x8*)(&Bs[wn * 128 + ct * 16 + l15][ks * 32 + lq * 8]);
        acc[ct] = __builtin_amdgcn_mfma_f32_16x16x32_f16(a[ks], bfr, acc[ct], 0, 0, 0);
      }
    }
    __syncthreads();
  }
#pragma unroll
  for (int ct = 0; ct < 8; ++ct) {
    int ncol = wn * 128 + ct * 16 + l15;
    float bvv = bias[ncol];
    int w_s = ncol >> 5, j_s = (ncol >> 4) & 1, i_s = ncol & 15;
#pragma unroll
    for (int r = 0; r < 4; ++r) {
      int m = m0 + wm * 16 + lq * 4 + r;  // m = b*512 + t
      int tt = m & 511, bb = m >> 9;
      int g_s = bb >> 2, lq_s = bb & 3;
      size_t idx = (((size_t)tt * 8 + g_s) * 8 + w_s) * 128 + (lq_s * 16 + i_s) * 2 + j_s;
      xp_packed[idx] = acc[ct][r] + bvv;
    }
  }
}

// ---------------------------------------------------------------------------
// RNN scan (R7 champion + T5 setprio): 8 blocks x 4 batches; 8 waves x 32 cols.
// setprio(1) around the ds_read+MFMA cluster, setprio(0) for the epilogue:
// the 2 waves/SIMD are phase-offset within a step, so the scheduler can
// prefer the MFMA-feeding wave while the other runs its VALU/trans tail.
// ---------------------------------------------------------------------------
__global__ __launch_bounds__(512, 2) void k_scan(
    const float* __restrict__ xp_packed,
    const _Float16* __restrict__ WhTp,    // [256 col][256 phys-k] permuted
    _Float16* __restrict__ Yt,            // [512][32][256 phys] f16
    float* __restrict__ hT)               // [32][256] fp32 (logical cols)
{
  __shared__ char hbuf[2][4224];
  const int tid = threadIdx.x;
  const int lane = tid & 63, w = tid >> 6;     // w = 0..7
  const int l15 = lane & 15, lq = lane >> 4;
  const int g = blockIdx.x;

  for (int i = tid; i < 2112; i += 512) ((float*)hbuf)[i] = 0.f;

  f16x8 bf[2][8];
#pragma unroll
  for (int j = 0; j < 2; ++j)
#pragma unroll
    for (int i = 0; i < 8; ++i) {
      int ks = (w + i) & 7;
      bf[j][i] = *(const f16x8*)(WhTp + (w * 32 + j * 16 + l15) * 256 + ks * 32 + lq * 8);
    }

  char* hz = (char*)&hbuf[0][0];
  const int rd_base = (l15 & 3) * 1056 + w * 64 + lq * 16;
  const int wr_base = lq * 1056 + w * 64 + l15 * 4;
  const bool m1 = (lq & 1) != 0, m2 = (lq & 2) != 0;

  const float* xpb = xp_packed + ((size_t)g * 8 + w) * 128 + lane * 2;
  _Float16* yb = Yt + ((size_t)(g * 4 + lq)) * 256 + w * 32 + l15 * 2;
  float* hTb = hT + (g * 4 + lq) * 256 + w * 32 + l15;

  __syncthreads();

  f32x2 x0 = *(const f32x2*)(xpb);
  f32x2 x1 = *(const f32x2*)(xpb + 8192);

#define SCAN_STEP(T, CUR, X, LAST)                                             \
  {                                                                            \
    const int t = (T);                                                         \
    f16x8 af[8];                                                               \
    af[0] = *(const f16x8*)(hz + rd_base + (CUR) * 4224 + 0 * 64);             \
    asm volatile("" ::: "memory");                                             \
    __builtin_amdgcn_s_barrier();                                              \
    asm volatile("" ::: "memory");                                             \
    __builtin_amdgcn_s_setprio(1);                                             \
    _Pragma("unroll")                                                          \
    for (int i = 1; i < 8; ++i)                                                \
      af[i] = *(const f16x8*)(hz + rd_base + (CUR) * 4224 + i * 64);           \
    f32x2 xcur = X;                                                            \
    f32x4 acc[2][4];                                                           \
    _Pragma("unroll")                                                          \
    for (int j = 0; j < 2; ++j) {                                              \
      _Pragma("unroll")                                                        \
      for (int c = 0; c < 4; ++c) {                                            \
        f32x4 zz = {0.f, 0.f, 0.f, 0.f};                                       \
        acc[j][c] = __builtin_amdgcn_mfma_f32_16x16x32_f16(af[2 * c], bf[j][2 * c], zz, 0, 0, 0); \
      }                                                                        \
    }                                                                          \
    { /* refill X for t+2 */                                                   \
      int tn = t + 2; if (tn > 511) tn = 511;                                  \
      X = *(const f32x2*)(xpb + (size_t)tn * 8192);                            \
    }                                                                          \
    _Pragma("unroll")                                                          \
    for (int j = 0; j < 2; ++j) {                                              \
      _Pragma("unroll")                                                        \
      for (int c = 0; c < 4; ++c)                                              \
        acc[j][c] = __builtin_amdgcn_mfma_f32_16x16x32_f16(af[2 * c + 1], bf[j][2 * c + 1], acc[j][c], 0, 0, 0); \
    }                                                                          \
    __builtin_amdgcn_s_setprio(0);                                             \
    f16x2 h2;                                                                  \
    float vv[2];                                                               \
    _Pragma("unroll")                                                          \
    for (int j = 0; j < 2; ++j) {                                              \
      f32x4 s01 = acc[j][0] + acc[j][1];                                       \
      f32x4 s23 = acc[j][2] + acc[j][3];                                       \
      f32x4 s = s01 + s23;                                                     \
      float t0 = m1 ? s[1] : s[0];                                             \
      float t1 = m1 ? s[3] : s[2];                                             \
      float v = tanh_fast((m2 ? t1 : t0) + xcur[j]);                           \
      vv[j] = v;                                                               \
      h2[j] = (_Float16)v;                                                     \
    }                                                                          \
    *(f16x2*)(hz + wr_base + ((CUR) ^ 1) * 4224) = h2;                         \
    *(f16x2*)(hz + wr_base + ((CUR) ^ 1) * 4224 + 512) = h2;                   \
    *(f16x2*)(yb + (size_t)t * 8192) = h2;                                     \
    if (LAST) {                                                                \
      hTb[0] = vv[0];                                                          \
      hTb[16] = vv[1];                                                         \
    }                                                                          \
    asm volatile("s_waitcnt lgkmcnt(0)" ::: "memory");                         \
  }

  SCAN_STEP(0, 0, x0, 0)
  for (int tp = 0; tp < 255; ++tp) {
    SCAN_STEP(2 * tp + 1, 1, x1, 0)
    SCAN_STEP(2 * tp + 2, 0, x0, 0)
  }
  SCAN_STEP(511, 1, x1, 1)
#undef SCAN_STEP
}

// ---------------------------------------------------------------------------
// GEMM3 + fused softmax. Half-K B-staging: Bs[128][136] (76.5KB total LDS
// -> 2 blocks/CU for cross-block latency hiding).
// ---------------------------------------------------------------------------
__global__ __launch_bounds__(512) void k_gemm3(
    const _Float16* __restrict__ Yt,    // [512][32][256 phys]
    const _Float16* __restrict__ WdTp,  // [1024][256 phys]
    const float* __restrict__ bd,       // [1024]
    float* __restrict__ out)            // [16384][1024]
{
  __shared__ _Float16 As[16][264];
  __shared__ _Float16 Bs[128][136];
  __shared__ _Float16 lg[16][1040];
  const int tid = threadIdx.x;
  const int lane = tid & 63, w = tid >> 6;
  const int l15 = lane & 15, lq = lane >> 4;
  const int m0 = blockIdx.x * 16;
  const int b = m0 >> 9, t0 = m0 & 511;

  {
    int r = tid >> 5, k8 = (tid & 31) * 8;
    *(f16x8*)(&As[r][k8]) = *(const f16x8*)(Yt + ((size_t)(t0 + r) * 32 + b) * 256 + k8);
  }
  __syncthreads();
  f16x8 a[8];
#pragma unroll
  for (int ks = 0; ks < 8; ++ks)
    a[ks] = *(const f16x8*)(&As[l15][ks * 32 + lq * 8]);

  for (int cc = 0; cc < 8; ++cc) {
    const int c0 = cc * 128;
    const int ncol = c0 + w * 16 + l15;
    f32x4 acc = {0.f, 0.f, 0.f, 0.f};
    __syncthreads();                     // protect Bs from prior readers
#pragma unroll
    for (int i = 0; i < 4; ++i) {        // stage K-half 0 (128 cols x 128 k)
      int q = i * 512 + tid;
      int n = q >> 4, k8 = (q & 15) * 8;
      *(f16x8*)(&Bs[n][k8]) = *(const f16x8*)(WdTp + (size_t)(c0 + n) * 256 + k8);
    }
    __syncthreads();
#pragma unroll
    for (int ks = 0; ks < 4; ++ks) {
      f16x8 bfr = *(const f16x8*)(&Bs[w * 16 + l15][ks * 32 + lq * 8]);
      acc = __builtin_amdgcn_mfma_f32_16x16x32_f16(a[ks], bfr, acc, 0, 0, 0);
    }
    __syncthreads();
#pragma unroll
    for (int i = 0; i < 4; ++i) {        // stage K-half 1
      int q = i * 512 + tid;
      int n = q >> 4, k8 = (q & 15) * 8;
      *(f16x8*)(&Bs[n][k8]) = *(const f16x8*)(WdTp + (size_t)(c0 + n) * 256 + 128 + k8);
    }
    __syncthreads();
#pragma unroll
    for (int ks = 4; ks < 8; ++ks) {
      f16x8 bfr = *(const f16x8*)(&Bs[w * 16 + l15][(ks - 4) * 32 + lq * 8]);
      acc = __builtin_amdgcn_mfma_f32_16x16x32_f16(a[ks], bfr, acc, 0, 0, 0);
    }
    float bvv = bd[ncol];
#pragma unroll
    for (int r = 0; r < 4; ++r)
      lg[lq * 4 + r][ncol] = (_Float16)(acc[r] + bvv);
  }
  __syncthreads();

  const int row = tid >> 5, j = tid & 31;
  float mx = -1e30f;
#pragma unroll
  for (int k = 0; k < 32; ++k)
    mx = fmaxf(mx, (float)lg[row][j + k * 32]);
#pragma unroll
  for (int m = 1; m < 32; m <<= 1)
    mx = fmaxf(mx, __shfl_xor(mx, m, 64));
  float s = 0.f;
#pragma unroll
  for (int k = 0; k < 32; ++k)
    s += __builtin_amdgcn_exp2f(((float)lg[row][j + k * 32] - mx) * 1.44269504088896f);
#pragma unroll
  for (int m = 1; m < 32; m <<= 1)
    s += __shfl_xor(s, m, 64);
  const float rinv = __builtin_amdgcn_rcpf(s);
  float* orow = out + (size_t)(m0 + row) * 1024;
#pragma unroll
  for (int k = 0; k < 8; ++k) {
    int c = k * 128 + j * 4;
    f32x4 vv;
#pragma unroll
    for (int u = 0; u < 4; ++u)
      vv[u] = __builtin_amdgcn_exp2f(((float)lg[row][c + u] - mx) * 1.44269504088896f) * rinv;
    *(f32x4*)(orow + c) = vv;
  }
}

// ---------------------------------------------------------------------------
extern "C" void kernel_launch(void* const* d_in, const int* in_sizes, int n_in,
                              void* d_out, int out_size, void* d_ws, size_t ws_size,
                              hipStream_t stream) {
  const float* X  = (const float*)d_in[0];
  const float* Wx = (const float*)d_in[1];
  const float* Wh = (const float*)d_in[2];
  const float* bv = (const float*)d_in[3];
  const float* Wd = (const float*)d_in[4];
  const float* bd = (const float*)d_in[5];
  float* out = (float*)d_out;

  char* ws = (char*)d_ws;
  float*    xp_packed = (float*)(ws);                              // 16 MB
  _Float16* Yt    = (_Float16*)(ws + (16u << 20));                 // 8 MB
  _Float16* WxT   = (_Float16*)(ws + (24u << 20));                 // 512 KB
  _Float16* WhTp  = (_Float16*)(ws + (24u << 20) + (512u << 10));  // 128 KB
  _Float16* WdTp  = (_Float16*)(ws + (24u << 20) + (640u << 10));  // 512 KB

  k_transpose_all<<<dim3(576), 256, 0, stream>>>(Wx, WxT, Wh, WhTp, Wd, WdTp);
  k_gemm1<<<dim3(512), 256, 0, stream>>>(X, WxT, bv, xp_packed);
  k_scan<<<dim3(8), 512, 0, stream>>>(xp_packed, WhTp, Yt, out + 16384 * 1024);
  k_gemm3<<<dim3(1024), 512, 0, stream>>>(Yt, WdTp, bd, out);
}

// Round 16
// 303.235 us; speedup vs baseline: 1.1537x; 1.0217x over previous
//
#include <hip/hip_runtime.h>

typedef float f32x4 __attribute__((ext_vector_type(4)));
typedef float f32x2 __attribute__((ext_vector_type(2)));
typedef _Float16 f16x8 __attribute__((ext_vector_type(8)));
typedef _Float16 f16x4 __attribute__((ext_vector_type(4)));
typedef _Float16 f16x2 __attribute__((ext_vector_type(2)));

__device__ __forceinline__ float tanh_fast(float x) {
  float e = __builtin_amdgcn_exp2f(x * 2.885390081777927f);
  return 1.0f - 2.0f * __builtin_amdgcn_rcpf(e + 1.0f);
}

// ---------------------------------------------------------------------------
// Merged transpose+cast kernel (one launch, 3 jobs by block range):
//   0..255   Wx  plain  (1024x256 -> WxT)
//   256..319 Wh  perm   (256x256  -> WhTp)
//   320..575 Wd  perm   (256x1024 -> WdTp)
// perm: out[c][pinv(r)], pinv(r) = (r&~31) | ((r&15)<<1) | ((r>>4)&1)
// ---------------------------------------------------------------------------
__global__ __launch_bounds__(256) void k_transpose_all(
    const float* __restrict__ Wx, _Float16* __restrict__ WxT,
    const float* __restrict__ Wh, _Float16* __restrict__ WhTp,
    const float* __restrict__ Wd, _Float16* __restrict__ WdTp)
{
  __shared__ float tile[32][33];
  const int b = blockIdx.x;
  const float* in; _Float16* outp; int R, C, bx, by, perm;
  if (b < 256)      { in = Wx; outp = WxT;  R = 1024; C = 256;  bx = b & 7;          by = b >> 3;          perm = 0; }
  else if (b < 320) { in = Wh; outp = WhTp; R = 256;  C = 256;  bx = (b - 256) & 7;  by = (b - 256) >> 3;  perm = 1; }
  else              { in = Wd; outp = WdTp; R = 256;  C = 1024; bx = (b - 320) & 31; by = (b - 320) >> 5;  perm = 1; }

  const int tx = threadIdx.x & 31, ty = threadIdx.x >> 5;
  const int tc = bx * 32, tr = by * 32;
#pragma unroll
  for (int i = 0; i < 32; i += 8)
    tile[ty + i][tx] = in[(size_t)(tr + ty + i) * C + tc + tx];
  __syncthreads();
  const int r = tr + tx;
  const int p = perm ? ((r & ~31) | ((r & 15) << 1) | ((r >> 4) & 1)) : r;
#pragma unroll
  for (int i = 0; i < 32; i += 8)
    outp[(size_t)(tc + ty + i) * R + p] = (_Float16)tile[tx][ty + i];
}

// ---------------------------------------------------------------------------
// GEMM1: xproj = X @ Wx + b, scattered into the scan's packed layout.
// BM=32 -> 512 blocks (2/CU, 42KB LDS).
//   idx = ((t*8 + g)*8 + w)*128 + (lq*16 + i)*2 + j
// ---------------------------------------------------------------------------
__global__ __launch_bounds__(256) void k_gemm1(
    const float* __restrict__ X, const _Float16* __restrict__ WxT,
    const float* __restrict__ bias, float* __restrict__ xp_packed)
{
  __shared__ _Float16 As[32][72];
  __shared__ _Float16 Bs[256][72];
  const int tid = threadIdx.x;
  const int lane = tid & 63, w = tid >> 6;
  const int l15 = lane & 15, lq = lane >> 4;
  const int m0 = blockIdx.x * 32;
  const int wm = w & 1, wn = w >> 1;

  f32x4 acc[8];
#pragma unroll
  for (int i = 0; i < 8; ++i) acc[i] = (f32x4){0.f, 0.f, 0.f, 0.f};

  for (int kc = 0; kc < 16; ++kc) {
    const int k0 = kc * 64;
#pragma unroll
    for (int it = 0; it < 2; ++it) {
      int q = tid + it * 256;
      int r = q >> 4, k4 = (q & 15) * 4;
      f32x4 v = *(const f32x4*)(X + (size_t)(m0 + r) * 1024 + k0 + k4);
      f16x4 hv;
      hv[0] = (_Float16)v[0]; hv[1] = (_Float16)v[1];
      hv[2] = (_Float16)v[2]; hv[3] = (_Float16)v[3];
      *(f16x4*)(&As[r][k4]) = hv;
    }
#pragma unroll
    for (int it = 0; it < 8; ++it) {
      int q = tid + it * 256;
      int n = q >> 3, k8 = (q & 7) * 8;
      *(f16x8*)(&Bs[n][k8]) = *(const f16x8*)(WxT + (size_t)n * 1024 + k0 + k8);
    }
    __syncthreads();
    f16x8 a[2];
#pragma unroll
    for (int ks = 0; ks < 2; ++ks)
      a[ks] = *(const f16x8*)(&As[wm * 16 + l15][ks * 32 + lq * 8]);
#pragma unroll
    for (int ct = 0; ct < 8; ++ct) {
#pragma unroll
      for (int ks = 0; ks < 2; ++ks) {
        f16x8 bfr = *(const f16x8*)(&Bs[wn * 128 + ct * 16 + l15][ks * 32 + lq * 8]);
        acc[ct] = __builtin_amdgcn_mfma_f32_16x16x32_f16(a[ks], bfr, acc[ct], 0, 0, 0);
      }
    }
    __syncthreads();
  }
#pragma unroll
  for (int ct = 0; ct < 8; ++ct) {
    int ncol = wn * 128 + ct * 16 + l15;
    float bvv = bias[ncol];
    int w_s = ncol >> 5, j_s = (ncol >> 4) & 1, i_s = ncol & 15;
#pragma unroll
    for (int r = 0; r < 4; ++r) {
      int m = m0 + wm * 16 + lq * 4 + r;
      int tt = m & 511, bb = m >> 9;
      int g_s = bb >> 2, lq_s = bb & 3;
      size_t idx = (((size_t)tt * 8 + g_s) * 8 + w_s) * 128 + (lq_s * 16 + i_s) * 2 + j_s;
      xp_packed[idx] = acc[ct][r] + bvv;
    }
  }
}

// ---------------------------------------------------------------------------
// RNN scan (R7 champion + T5 + pinned-bf): 8 blocks x 4 batches; 8 waves x 32.
// bf held in 16 NAMED registers, made opaque via identity asm so the compiler
// cannot rematerialize them from global memory inside the 512-step loop.
// Reads use 8 per-ordinal wrap offsets (no dup region write).
// ---------------------------------------------------------------------------
__global__ __launch_bounds__(512, 2) void k_scan(
    const float* __restrict__ xp_packed,
    const _Float16* __restrict__ WhTp,    // [256 col][256 phys-k] permuted
    _Float16* __restrict__ Yt,            // [512][32][256 phys] f16
    float* __restrict__ hT)               // [32][256] fp32 (logical cols)
{
  __shared__ char hbuf[2][4224];
  const int tid = threadIdx.x;
  const int lane = tid & 63, w = tid >> 6;     // w = 0..7
  const int l15 = lane & 15, lq = lane >> 4;
  const int g = blockIdx.x;

  for (int i = tid; i < 2112; i += 512) ((float*)hbuf)[i] = 0.f;

#define LDB(J, I) \
  (*(const f16x8*)(WhTp + (w * 32 + (J) * 16 + l15) * 256 + ((w + (I)) & 7) * 32 + lq * 8))
  f16x8 bfa0 = LDB(0, 0), bfa1 = LDB(0, 1), bfa2 = LDB(0, 2), bfa3 = LDB(0, 3);
  f16x8 bfa4 = LDB(0, 4), bfa5 = LDB(0, 5), bfa6 = LDB(0, 6), bfa7 = LDB(0, 7);
  f16x8 bfb0 = LDB(1, 0), bfb1 = LDB(1, 1), bfb2 = LDB(1, 2), bfb3 = LDB(1, 3);
  f16x8 bfb4 = LDB(1, 4), bfb5 = LDB(1, 5), bfb6 = LDB(1, 6), bfb7 = LDB(1, 7);
#undef LDB
  // opaque-ify: values no longer provably equal memory -> must stay in regs
  asm volatile("" : "+v"(bfa0), "+v"(bfa1), "+v"(bfa2), "+v"(bfa3));
  asm volatile("" : "+v"(bfa4), "+v"(bfa5), "+v"(bfa6), "+v"(bfa7));
  asm volatile("" : "+v"(bfb0), "+v"(bfb1), "+v"(bfb2), "+v"(bfb3));
  asm volatile("" : "+v"(bfb4), "+v"(bfb5), "+v"(bfb6), "+v"(bfb7));

  char* hz = (char*)&hbuf[0][0];
  // per-ordinal read offsets (batch row l15&3, slice (w+i)&7, k-sub lq)
  int ro[8];
#pragma unroll
  for (int i = 0; i < 8; ++i)
    ro[i] = (l15 & 3) * 1056 + ((w + i) & 7) * 64 + lq * 16;
  const int wr_base = lq * 1056 + w * 64 + l15 * 4;
  const bool m1 = (lq & 1) != 0, m2 = (lq & 2) != 0;

  const float* xpb = xp_packed + ((size_t)g * 8 + w) * 128 + lane * 2;
  _Float16* yb = Yt + ((size_t)(g * 4 + lq)) * 256 + w * 32 + l15 * 2;
  float* hTb = hT + (g * 4 + lq) * 256 + w * 32 + l15;

  __syncthreads();

  f32x2 x0 = *(const f32x2*)(xpb);
  f32x2 x1 = *(const f32x2*)(xpb + 8192);

#define MF(A, B, C) __builtin_amdgcn_mfma_f32_16x16x32_f16((A), (B), (C), 0, 0, 0)
#define SCAN_STEP(T, CUR, X, LAST)                                             \
  {                                                                            \
    const int t = (T);                                                         \
    f16x8 af[8];                                                               \
    af[0] = *(const f16x8*)(hz + ro[0] + (CUR) * 4224);                        \
    asm volatile("" ::: "memory");                                             \
    __builtin_amdgcn_s_barrier();                                              \
    asm volatile("" ::: "memory");                                             \
    __builtin_amdgcn_s_setprio(1);                                             \
    _Pragma("unroll")                                                          \
    for (int i = 1; i < 8; ++i)                                                \
      af[i] = *(const f16x8*)(hz + ro[i] + (CUR) * 4224);                      \
    f32x2 xcur = X;                                                            \
    f32x4 zz = {0.f, 0.f, 0.f, 0.f};                                           \
    f32x4 acc[2][4];                                                           \
    acc[0][0] = MF(af[0], bfa0, zz); acc[1][0] = MF(af[0], bfb0, zz);          \
    acc[0][1] = MF(af[2], bfa2, zz); acc[1][1] = MF(af[2], bfb2, zz);          \
    acc[0][2] = MF(af[4], bfa4, zz); acc[1][2] = MF(af[4], bfb4, zz);          \
    acc[0][3] = MF(af[6], bfa6, zz); acc[1][3] = MF(af[6], bfb6, zz);          \
    { /* refill X for t+2 */                                                   \
      int tn = t + 2; if (tn > 511) tn = 511;                                  \
      X = *(const f32x2*)(xpb + (size_t)tn * 8192);                            \
    }                                                                          \
    acc[0][0] = MF(af[1], bfa1, acc[0][0]); acc[1][0] = MF(af[1], bfb1, acc[1][0]); \
    acc[0][1] = MF(af[3], bfa3, acc[0][1]); acc[1][1] = MF(af[3], bfb3, acc[1][1]); \
    acc[0][2] = MF(af[5], bfa5, acc[0][2]); acc[1][2] = MF(af[5], bfb5, acc[1][2]); \
    acc[0][3] = MF(af[7], bfa7, acc[0][3]); acc[1][3] = MF(af[7], bfb7, acc[1][3]); \
    __builtin_amdgcn_s_setprio(0);                                             \
    f16x2 h2;                                                                  \
    float vv[2];                                                               \
    _Pragma("unroll")                                                          \
    for (int j = 0; j < 2; ++j) {                                              \
      f32x4 s01 = acc[j][0] + acc[j][1];                                       \
      f32x4 s23 = acc[j][2] + acc[j][3];                                       \
      f32x4 s = s01 + s23;                                                     \
      float t0 = m1 ? s[1] : s[0];                                             \
      float t1 = m1 ? s[3] : s[2];                                             \
      float v = tanh_fast((m2 ? t1 : t0) + xcur[j]);                           \
      vv[j] = v;                                                               \
      h2[j] = (_Float16)v;                                                     \
    }                                                                          \
    *(f16x2*)(hz + wr_base + ((CUR) ^ 1) * 4224) = h2;                         \
    *(f16x2*)(yb + (size_t)t * 8192) = h2;                                     \
    if (LAST) {                                                                \
      hTb[0] = vv[0];                                                          \
      hTb[16] = vv[1];                                                         \
    }                                                                          \
    asm volatile("s_waitcnt lgkmcnt(0)" ::: "memory");                         \
  }

  SCAN_STEP(0, 0, x0, 0)
  for (int tp = 0; tp < 255; ++tp) {
    SCAN_STEP(2 * tp + 1, 1, x1, 0)
    SCAN_STEP(2 * tp + 2, 0, x0, 0)
  }
  SCAN_STEP(511, 1, x1, 1)
#undef SCAN_STEP
#undef MF
}

// ---------------------------------------------------------------------------
// GEMM3 + fused softmax (R14-verified version). Half-K B-staging:
// Bs[128][136] (76.5KB total LDS -> 2 blocks/CU).
// ---------------------------------------------------------------------------
__global__ __launch_bounds__(512) void k_gemm3(
    const _Float16* __restrict__ Yt,    // [512][32][256 phys]
    const _Float16* __restrict__ WdTp,  // [1024][256 phys]
    const float* __restrict__ bd,       // [1024]
    float* __restrict__ out)            // [16384][1024]
{
  __shared__ _Float16 As[16][264];
  __shared__ _Float16 Bs[128][136];
  __shared__ _Float16 lg[16][1040];
  const int tid = threadIdx.x;
  const int lane = tid & 63, w = tid >> 6;
  const int l15 = lane & 15, lq = lane >> 4;
  const int m0 = blockIdx.x * 16;
  const int b = m0 >> 9, t0 = m0 & 511;

  {
    int r = tid >> 5, k8 = (tid & 31) * 8;
    *(f16x8*)(&As[r][k8]) = *(const f16x8*)(Yt + ((size_t)(t0 + r) * 32 + b) * 256 + k8);
  }
  __syncthreads();
  f16x8 a[8];
#pragma unroll
  for (int ks = 0; ks < 8; ++ks)
    a[ks] = *(const f16x8*)(&As[l15][ks * 32 + lq * 8]);

  for (int cc = 0; cc < 8; ++cc) {
    const int c0 = cc * 128;
    const int ncol = c0 + w * 16 + l15;
    f32x4 acc = {0.f, 0.f, 0.f, 0.f};
    __syncthreads();                     // protect Bs from prior readers
#pragma unroll
    for (int i = 0; i < 4; ++i) {        // stage K-half 0 (128 cols x 128 k)
      int q = i * 512 + tid;
      int n = q >> 4, k8 = (q & 15) * 8;
      *(f16x8*)(&Bs[n][k8]) = *(const f16x8*)(WdTp + (size_t)(c0 + n) * 256 + k8);
    }
    __syncthreads();
#pragma unroll
    for (int ks = 0; ks < 4; ++ks) {
      f16x8 bfr = *(const f16x8*)(&Bs[w * 16 + l15][ks * 32 + lq * 8]);
      acc = __builtin_amdgcn_mfma_f32_16x16x32_f16(a[ks], bfr, acc, 0, 0, 0);
    }
    __syncthreads();
#pragma unroll
    for (int i = 0; i < 4; ++i) {        // stage K-half 1
      int q = i * 512 + tid;
      int n = q >> 4, k8 = (q & 15) * 8;
      *(f16x8*)(&Bs[n][k8]) = *(const f16x8*)(WdTp + (size_t)(c0 + n) * 256 + 128 + k8);
    }
    __syncthreads();
#pragma unroll
    for (int ks = 4; ks < 8; ++ks) {
      f16x8 bfr = *(const f16x8*)(&Bs[w * 16 + l15][(ks - 4) * 32 + lq * 8]);
      acc = __builtin_amdgcn_mfma_f32_16x16x32_f16(a[ks], bfr, acc, 0, 0, 0);
    }
    float bvv = bd[ncol];
#pragma unroll
    for (int r = 0; r < 4; ++r)
      lg[lq * 4 + r][ncol] = (_Float16)(acc[r] + bvv);
  }
  __syncthreads();

  const int row = tid >> 5, j = tid & 31;
  float mx = -1e30f;
#pragma unroll
  for (int k = 0; k < 32; ++k)
    mx = fmaxf(mx, (float)lg[row][j + k * 32]);
#pragma unroll
  for (int m = 1; m < 32; m <<= 1)
    mx = fmaxf(mx, __shfl_xor(mx, m, 64));
  float s = 0.f;
#pragma unroll
  for (int k = 0; k < 32; ++k)
    s += __builtin_amdgcn_exp2f(((float)lg[row][j + k * 32] - mx) * 1.44269504088896f);
#pragma unroll
  for (int m = 1; m < 32; m <<= 1)
    s += __shfl_xor(s, m, 64);
  const float rinv = __builtin_amdgcn_rcpf(s);
  float* orow = out + (size_t)(m0 + row) * 1024;
#pragma unroll
  for (int k = 0; k < 8; ++k) {
    int c = k * 128 + j * 4;
    f32x4 vv;
#pragma unroll
    for (int u = 0; u < 4; ++u)
      vv[u] = __builtin_amdgcn_exp2f(((float)lg[row][c + u] - mx) * 1.44269504088896f) * rinv;
    *(f32x4*)(orow + c) = vv;
  }
}

// ---------------------------------------------------------------------------
extern "C" void kernel_launch(void* const* d_in, const int* in_sizes, int n_in,
                              void* d_out, int out_size, void* d_ws, size_t ws_size,
                              hipStream_t stream) {
  const float* X  = (const float*)d_in[0];
  const float* Wx = (const float*)d_in[1];
  const float* Wh = (const float*)d_in[2];
  const float* bv = (const float*)d_in[3];
  const float* Wd = (const float*)d_in[4];
  const float* bd = (const float*)d_in[5];
  float* out = (float*)d_out;

  char* ws = (char*)d_ws;
  float*    xp_packed = (float*)(ws);                              // 16 MB
  _Float16* Yt    = (_Float16*)(ws + (16u << 20));                 // 8 MB
  _Float16* WxT   = (_Float16*)(ws + (24u << 20));                 // 512 KB
  _Float16* WhTp  = (_Float16*)(ws + (24u << 20) + (512u << 10));  // 128 KB
  _Float16* WdTp  = (_Float16*)(ws + (24u << 20) + (640u << 10));  // 512 KB

  k_transpose_all<<<dim3(576), 256, 0, stream>>>(Wx, WxT, Wh, WhTp, Wd, WdTp);
  k_gemm1<<<dim3(512), 256, 0, stream>>>(X, WxT, bv, xp_packed);
  k_scan<<<dim3(8), 512, 0, stream>>>(xp_packed, WhTp, Yt, out + 16384 * 1024);
  k_gemm3<<<dim3(1024), 512, 0, stream>>>(Yt, WdTp, bd, out);
}